// Round 12
// baseline (84.096 us; speedup 1.0000x reference)
//
#include <hip/hip_runtime.h>
#include <hip/hip_bf16.h>

#define TT 512
#define BB 64
#define KK 10
#define DD 1024
#define CL 32   // chunk length (steps per chunk)
#define NC 16   // number of chunks

#define AS1 __attribute__((address_space(1)))
#define AS3 __attribute__((address_space(3)))

typedef unsigned char uchar;
typedef short bf16x8 __attribute__((ext_vector_type(8)));
typedef float f32x4 __attribute__((ext_vector_type(4)));

__device__ __forceinline__ unsigned f2bf(float f) {  // RNE f32 -> bf16 bits
    unsigned u = __float_as_uint(f);
    return (u + 0x7FFFu + ((u >> 16) & 1u)) >> 16;
}

__device__ __forceinline__ float max10(const float* r) {
    float m0 = fmaxf(r[0], r[1]), m1 = fmaxf(r[2], r[3]);
    float m2 = fmaxf(r[4], r[5]), m3 = fmaxf(r[6], r[7]);
    float m4 = fmaxf(r[8], r[9]);
    m0 = fmaxf(m0, m1); m2 = fmaxf(m2, m3); m0 = fmaxf(m0, m2);
    return fmaxf(m0, m4);
}

__device__ __forceinline__ float lse10(const float* r) {
    const float m = max10(r);
    float s0 = __expf(r[0] - m) + __expf(r[1] - m);
    float s1 = __expf(r[2] - m) + __expf(r[3] - m);
    float s2 = __expf(r[4] - m) + __expf(r[5] - m);
    float s3 = __expf(r[6] - m) + __expf(r[7] - m);
    float s4 = __expf(r[8] - m) + __expf(r[9] - m);
    return m + __logf(((s0 + s1) + (s2 + s3)) + s4);
}

// ---------------- Kernel A: global_load_lds-staged MFMA emissions -----------
// 256 blocks x 512 thr (8 waves). Block = 128 rows; wave owns 16 rows.
// K=1024 in 16 phases of 64. Per phase, each wave issues 4 global_load_lds
// (16B, VGPR-free DMA) into ITS OWN double-buffered LDS slab -> no barriers in
// the loop, counted vmcnt(4) only. 64 KB/CU in flight (vs ~1KB VGPR-bound).
// Source XOR pre-swizzle (chunk ^ row&7) + swizzled ds_read = conflict-free.
// block 256: lengths per batch + zero loss slot.
__global__ __launch_bounds__(512) void k_emissions(
    const int* __restrict__ words, const float* __restrict__ wf,
    const float* __restrict__ W, const float* __restrict__ bias,
    float* __restrict__ em, int* __restrict__ lenArr, float* loss_slot) {
    __shared__ char  Ab[2][8][4096];   // 64 KB: [buf][wave][16 rows x 256B]
    __shared__ uint4 Bfrag[32][64];    // 32 KB W fragment table

    const int tid = threadIdx.x;
    if (blockIdx.x == 256) {  // lengths + loss init
        int* cnt = (int*)&Ab[0][0][0];           // reuse LDS: cnt[8][64]
        const int b = tid & 63, seg = tid >> 6;
        int c = 0;
        for (int t = seg; t < TT; t += 8) c += (words[t * BB + b] != 0) ? 1 : 0;
        cnt[seg * 64 + b] = c;
        __syncthreads();
        if (tid < 64) {
            int s = 0;
            #pragma unroll
            for (int g = 0; g < 8; ++g) s += cnt[g * 64 + tid];
            lenArr[tid] = s;
        }
        if (tid == 0) *loss_slot = 0.f;
        return;
    }

    // B-fragment table: Bfrag[ks][lane] = 8 bf16 of W[ks*32+(lane>>4)*8+p][lane&15]
    for (int idx = tid; idx < 32 * 64; idx += 512) {
        const int ks = idx >> 6, l = idx & 63;
        const int col = l & 15, kg2 = l >> 4;
        unsigned u[4];
        #pragma unroll
        for (int p = 0; p < 4; ++p) {
            unsigned lo = 0, hi = 0;
            if (col < KK) {
                const int k0 = ks * 32 + kg2 * 8 + p * 2;
                lo = f2bf(W[(size_t)k0 * KK + col]);
                hi = f2bf(W[(size_t)(k0 + 1) * KK + col]);
            }
            u[p] = lo | (hi << 16);
        }
        Bfrag[ks][l] = make_uint4(u[0], u[1], u[2], u[3]);
    }
    __syncthreads();

    const int wave = tid >> 6, lane = tid & 63;
    const int arow = lane & 15;      // A row within tile (== C col)
    const int kg   = lane >> 4;      // k-group (and C row-group)
    const int row0 = blockIdx.x * 128 + wave * 16;
    const float bk = bias[arow < KK ? arow : 0];

    // DMA source pointers: instruction i covers rows i*4+(lane>>4); lane's
    // 16B chunk is XOR-preswizzled so LDS[row][c] holds global chunk c^(row&7).
    const int rr = lane >> 4;        // row within instruction (0..3)
    const int cc = lane & 15;        // chunk slot within row (0..15)
    const float* gsrc[4];
    #pragma unroll
    for (int i = 0; i < 4; ++i) {
        const int rloc = i * 4 + rr;
        gsrc[i] = wf + (size_t)(row0 + rloc) * DD + (cc ^ (rloc & 7)) * 4;
    }

#define ISSUE(P, B) do { \
    _Pragma("unroll") \
    for (int i_ = 0; i_ < 4; ++i_) { \
        __builtin_amdgcn_global_load_lds( \
            (const AS1 unsigned int*)(gsrc[i_] + (P) * 64), \
            (AS3 unsigned int*)&Ab[B][wave][i_ * 1024], 16, 0, 0); \
    } \
} while (0)

    ISSUE(0, 0);
    ISSUE(1, 1);

    f32x4 acc = {0.f, 0.f, 0.f, 0.f};
    const int sw = arow & 7;
    const char* slab = &Ab[0][wave][0];           // buf stride = 32768 B
    const int rbase = arow * 256;

    #pragma unroll 1
    for (int p = 0; p < 16; ++p) {
        const int b = p & 1;
        if (p < 15) { asm volatile("s_waitcnt vmcnt(4)" ::: "memory"); }
        else        { asm volatile("s_waitcnt vmcnt(0)" ::: "memory"); }
        __builtin_amdgcn_sched_barrier(0);

        const char* rb = slab + b * 32768 + rbase;
        f32x4 fa0, fb0, fa1, fb1;
        uint4 B0, B1;
        {   // ks = 0: global chunks kg*2, kg*2+1
            fa0 = *(const f32x4*)(rb + (((kg * 2)     ^ sw) << 4));
            fb0 = *(const f32x4*)(rb + (((kg * 2 + 1) ^ sw) << 4));
            B0 = Bfrag[p * 2][lane];
        }
        {   // ks = 1: global chunks 8+kg*2, 8+kg*2+1
            fa1 = *(const f32x4*)(rb + (((8 + kg * 2)     ^ sw) << 4));
            fb1 = *(const f32x4*)(rb + (((8 + kg * 2 + 1) ^ sw) << 4));
            B1 = Bfrag[p * 2 + 1][lane];
        }
        asm volatile("s_waitcnt lgkmcnt(0)" ::: "memory");
        __builtin_amdgcn_sched_barrier(0);
        if (p < 14) ISSUE(p + 2, b);   // refill the buffer just consumed

        bf16x8 a0, a1;
        a0[0] = (short)f2bf(fa0[0]); a0[1] = (short)f2bf(fa0[1]);
        a0[2] = (short)f2bf(fa0[2]); a0[3] = (short)f2bf(fa0[3]);
        a0[4] = (short)f2bf(fb0[0]); a0[5] = (short)f2bf(fb0[1]);
        a0[6] = (short)f2bf(fb0[2]); a0[7] = (short)f2bf(fb0[3]);
        a1[0] = (short)f2bf(fa1[0]); a1[1] = (short)f2bf(fa1[1]);
        a1[2] = (short)f2bf(fa1[2]); a1[3] = (short)f2bf(fa1[3]);
        a1[4] = (short)f2bf(fb1[0]); a1[5] = (short)f2bf(fb1[1]);
        a1[6] = (short)f2bf(fb1[2]); a1[7] = (short)f2bf(fb1[3]);
        union { uint4 u; bf16x8 v; } bu0, bu1;
        bu0.u = B0; bu1.u = B1;
        acc = __builtin_amdgcn_mfma_f32_16x16x32_bf16(a0, bu0.v, acc, 0, 0, 0);
        acc = __builtin_amdgcn_mfma_f32_16x16x32_bf16(a1, bu1.v, acc, 0, 0, 0);
    }
#undef ISSUE

    // C layout: col = lane&15, row = (lane>>4)*4 + reg  [m89]
    if (arow < KK) {
        #pragma unroll
        for (int r = 0; r < 4; ++r)
            em[(size_t)(row0 + kg * 4 + r) * KK + arow] = acc[r] + bk;
    }
}

// ---------------- Kernel B: per-chunk 10x10 transfer matrices ---------------
// grid 2048: blockIdx = sem*1024 + b*16 + c; 128 threads, (i,j) = tid/10,tid%10.
__global__ __launch_bounds__(128) void k_chunk(
    const float* __restrict__ em, const float* __restrict__ trans,
    const int* __restrict__ lenArr, float* __restrict__ Mlse, float* __restrict__ Mmax) {
    int id = blockIdx.x;
    const bool mx = id >= 1024; id &= 1023;
    const int b = id >> 4, c = id & 15;
    const int len = lenArr[b];
    const int s_lo = c * CL + 1;
    const int s_hi = min(c * CL + CL, len - 1);
    const int ns = s_hi - s_lo + 1;
    if (ns <= 0) return;  // identity chunk: consumers skip it

    __shared__ float Ms[KK][12];
    __shared__ float eml[CL][KK];
    const int tid = threadIdx.x;
    for (int idx = tid; idx < CL * KK; idx += 128) {
        const int sl = idx / KK, j = idx % KK;
        const int s = s_lo + sl;
        eml[sl][j] = (s <= TT - 1) ? em[((size_t)s * BB + b) * KK + j] : 0.f;
    }
    const int i = tid / KK, j = tid % KK;
    const bool act = tid < KK * KK;
    float trc[KK];
    if (act) {
        #pragma unroll
        for (int k = 0; k < KK; ++k) trc[k] = trans[k * KK + j];
    }
    __syncthreads();
    float cur = 0.f;
    if (act) { cur = trans[i * KK + j] + eml[0][j]; Ms[i][j] = cur; }
    __syncthreads();
    for (int sl = 1; sl < ns; ++sl) {
        float row[KK];
        if (act) {
            #pragma unroll
            for (int k = 0; k < KK; ++k) row[k] = Ms[i][k] + trc[k];
        }
        __syncthreads();
        if (act) {
            cur = (mx ? max10(row) : lse10(row)) + eml[sl][j];
            Ms[i][j] = cur;
        }
        __syncthreads();
    }
    if (act) {
        float* out = mx ? Mmax : Mlse;
        out[((size_t)b * NC + c) * 100 + i * KK + j] = cur;
    }
}

// ---------------- Kernel C: merged fold + hist + backtrace + loss -----------
// grid 64 (one block per batch) x 1024 threads (16 waves).
__global__ __launch_bounds__(1024) void k_crf(
    const int* __restrict__ tags, const float* __restrict__ em,
    const float* __restrict__ startv, const float* __restrict__ endv,
    const float* __restrict__ trans, const int* __restrict__ lenArr,
    const float* __restrict__ Mlse, const float* __restrict__ Mmax,
    int* __restrict__ paths, float* __restrict__ loss_slot) {
    const int b = blockIdx.x;
    const int tid = threadIdx.x;
    const int wv = tid >> 6, lane = tid & 63;
    const int len = lenArr[b];

    __shared__ float Ml[NC][100];
    __shared__ float Mm[NC][100];
    __shared__ float eml[NC][CL][KK];
    __shared__ float ub[NC][KK];
    __shared__ uchar hl[NC][CL * KK];
    __shared__ int   Fl[NC][KK];
    __shared__ int   vt[NC + 1];
    __shared__ float em0[KK];
    __shared__ float red[2];

    for (int idx = tid; idx < NC * 100; idx += 1024) {
        Ml[idx / 100][idx % 100] = Mlse[(size_t)b * NC * 100 + idx];
        Mm[idx / 100][idx % 100] = Mmax[(size_t)b * NC * 100 + idx];
    }
    for (int idx = tid; idx < NC * CL * KK; idx += 1024) {
        const int c = idx / (CL * KK), r = idx % (CL * KK);
        const int sl = r / KK, j = r % KK;
        const int s = c * CL + 1 + sl;
        eml[c][sl][j] = (s <= TT - 1) ? em[((size_t)s * BB + b) * KK + j] : 0.f;
    }
    if (tid < KK) em0[tid] = em[(size_t)b * KK + tid];
    __syncthreads();

    if (wv == 0) {  // max-plus fold -> boundary vectors + last tag
        float v[KK];
        #pragma unroll
        for (int i = 0; i < KK; ++i) v[i] = startv[i] + em0[i];
        for (int c = 0; c < NC; ++c) {
            if (lane < KK) ub[c][lane] = v[lane];
            const int s_hi = min(c * CL + CL, len - 1);
            if (s_hi >= c * CL + 1) {
                float nv = 0.f;
                if (lane < KK) {
                    float r[KK];
                    #pragma unroll
                    for (int k = 0; k < KK; ++k) r[k] = v[k] + Mm[c][k * KK + lane];
                    nv = max10(r);
                }
                #pragma unroll
                for (int i = 0; i < KK; ++i) v[i] = __shfl(nv, i);
            }
        }
        float best = v[0] + endv[0];
        int bi = 0;
        #pragma unroll
        for (int i = 1; i < KK; ++i) {
            const float x = v[i] + endv[i];
            if (x > best) { best = x; bi = i; }
        }
        if (lane == 0) vt[NC] = bi;
    } else if (wv == 1) {  // LSE fold -> denominator
        float v[KK];
        #pragma unroll
        for (int i = 0; i < KK; ++i) v[i] = startv[i] + em0[i];
        for (int c = 0; c < NC; ++c) {
            const int s_hi = min(c * CL + CL, len - 1);
            if (s_hi >= c * CL + 1) {
                float nv = 0.f;
                if (lane < KK) {
                    float r[KK];
                    #pragma unroll
                    for (int k = 0; k < KK; ++k) r[k] = v[k] + Ml[c][k * KK + lane];
                    nv = lse10(r);
                }
                #pragma unroll
                for (int i = 0; i < KK; ++i) v[i] = __shfl(nv, i);
            }
        }
        float r[KK];
        #pragma unroll
        for (int i = 0; i < KK; ++i) r[i] = v[i] + endv[i];
        if (lane == 0) red[0] = lse10(r);
    } else if (wv == 2) {  // gold-path numerator
        float part = 0.f;
        for (int t = 1 + lane; t < len; t += 64) {
            const int tp = tags[(t - 1) * BB + b];
            const int tc = tags[t * BB + b];
            part += trans[tp * KK + tc] + eml[(t - 1) >> 5][(t - 1) & 31][tc];
        }
        #pragma unroll
        for (int off = 32; off >= 1; off >>= 1) part += __shfl_xor(part, off);
        if (lane == 0) {
            const int t0 = tags[b];
            const int te = tags[(len - 1) * BB + b];
            red[1] = part + startv[t0] + em0[t0] + endv[te];
        }
    }
    __syncthreads();

    // per-chunk Viterbi re-run from exact boundary vector (wave c owns chunk c)
    {
        const int c = wv;
        const int s_hi = min(c * CL + CL, len - 1);
        const int ns = s_hi - (c * CL + 1) + 1;
        if (ns > 0) {
            float trc[KK];
            if (lane < KK) {
                #pragma unroll
                for (int i = 0; i < KK; ++i) trc[i] = trans[i * KK + lane];
            }
            float s[KK];
            #pragma unroll
            for (int i = 0; i < KK; ++i) s[i] = ub[c][i];
            for (int sl = 0; sl < ns; ++sl) {
                float best = s[0] + trc[0];
                int bi = 0;
                #pragma unroll
                for (int i = 1; i < KK; ++i) {
                    const float x = s[i] + trc[i];
                    if (x > best) { best = x; bi = i; }
                }
                float snew = 0.f;
                if (lane < KK) {
                    snew = best + eml[c][sl][lane];
                    hl[c][sl * KK + lane] = (uchar)bi;
                }
                #pragma unroll
                for (int i = 0; i < KK; ++i) s[i] = __shfl(snew, i);
            }
            if (lane < KK) {
                int cur = lane;
                for (int sl = ns - 1; sl >= 0; --sl) cur = hl[c][sl * KK + cur];
                Fl[c][lane] = cur;
            }
        }
    }
    __syncthreads();

    if (tid == 0) {  // boundary-tag fold + loss
        int cur = vt[NC];
        for (int c = NC - 1; c >= 0; --c) {
            const int s_hi = min(c * CL + CL, len - 1);
            if (s_hi >= c * CL + 1) cur = Fl[c][cur];
            vt[c] = cur;
        }
        atomicAdd(loss_slot, red[0] - red[1]);
    }
    __syncthreads();

    // emit: wave w writes path slice [32w, 32w+31]
    const int t0 = wv * CL;
    if (lane < CL) {
        const int t = t0 + lane;
        if (t >= len) paths[t * BB + b] = 0;
    }
    if (lane == 0) {
        const int a = min(t0 + CL, len - 1);
        if (a >= t0) {
            int cur = vt[wv + 1];  // = path[a]
            for (int t = a; t >= t0; --t) {
                if (t <= t0 + CL - 1) paths[t * BB + b] = cur;
                if (t > t0) cur = (int)hl[wv][(t - t0 - 1) * KK + cur];
            }
        }
    }
}

extern "C" void kernel_launch(void* const* d_in, const int* in_sizes, int n_in,
                              void* d_out, int out_size, void* d_ws, size_t ws_size,
                              hipStream_t stream) {
    const int*   words  = (const int*)d_in[0];
    const int*   tags   = (const int*)d_in[1];
    const float* wf     = (const float*)d_in[2];
    const float* W      = (const float*)d_in[3];
    const float* bias   = (const float*)d_in[4];
    const float* startv = (const float*)d_in[5];
    const float* endv   = (const float*)d_in[6];
    const float* trans  = (const float*)d_in[7];

    float* em   = (float*)d_ws;                       // 512*64*10 floats
    float* Mlse = em + 327680;                        // 64*16*100
    float* Mmax = Mlse + 102400;                      // 64*16*100
    int*   lenA = (int*)(Mmax + 102400);              // 64

    int*   paths     = (int*)d_out;                   // (T,B) int32 values
    float* loss_slot = ((float*)d_out) + TT * BB;     // scalar f32

    k_emissions<<<257, 512, 0, stream>>>(words, wf, W, bias, em, lenA, loss_slot);
    k_chunk<<<2048, 128, 0, stream>>>(em, trans, lenA, Mlse, Mmax);
    k_crf<<<64, 1024, 0, stream>>>(tags, em, startv, endv, trans, lenA,
                                   Mlse, Mmax, paths, loss_slot);
}

// Round 13
// 78.062 us; speedup vs baseline: 1.0773x; 1.0773x over previous
//
#include <hip/hip_runtime.h>
#include <hip/hip_bf16.h>

#define TT 512
#define BB 64
#define KK 10
#define DD 1024
#define CL 32   // chunk length (steps per chunk)
#define NC 16   // number of chunks

typedef unsigned char uchar;
typedef short bf16x8 __attribute__((ext_vector_type(8)));
typedef float f32x4 __attribute__((ext_vector_type(4)));

__device__ __forceinline__ unsigned f2bf(float f) {  // RNE f32 -> bf16 bits
    unsigned u = __float_as_uint(f);
    return (u + 0x7FFFu + ((u >> 16) & 1u)) >> 16;
}

__device__ __forceinline__ float max10(const float* r) {
    float m0 = fmaxf(r[0], r[1]), m1 = fmaxf(r[2], r[3]);
    float m2 = fmaxf(r[4], r[5]), m3 = fmaxf(r[6], r[7]);
    float m4 = fmaxf(r[8], r[9]);
    m0 = fmaxf(m0, m1); m2 = fmaxf(m2, m3); m0 = fmaxf(m0, m2);
    return fmaxf(m0, m4);
}

__device__ __forceinline__ float lse10(const float* r) {
    const float m = max10(r);
    float s0 = __expf(r[0] - m) + __expf(r[1] - m);
    float s1 = __expf(r[2] - m) + __expf(r[3] - m);
    float s2 = __expf(r[4] - m) + __expf(r[5] - m);
    float s3 = __expf(r[6] - m) + __expf(r[7] - m);
    float s4 = __expf(r[8] - m) + __expf(r[9] - m);
    return m + __logf(((s0 + s1) + (s2 + s3)) + s4);
}

// ---------------- Kernel A: emissions via MFMA + lengths (R6 champion) ------
// blocks 0..255: 128 rows (8 waves x one 16x16 tile, K=1024). B-fragments
// register-resident (phase double-buffered from LDS); A direct per-lane gather
// with 4-deep ring prefetch — empirically the fastest wf-read structure in
// this container (engages HBM + L3 read paths concurrently, ~2.3 TB/s eff).
// block 256: lengths per batch + zero loss slot.
__global__ __launch_bounds__(512) void k_emissions(
    const int* __restrict__ words, const float* __restrict__ wf,
    const float* __restrict__ W, const float* __restrict__ bias,
    float* __restrict__ em, int* __restrict__ lenArr, float* loss_slot) {
    const int tid = threadIdx.x;
    if (blockIdx.x == 256) {
        __shared__ int cnt[8][64];
        const int b = tid & 63, seg = tid >> 6;
        int c = 0;
        for (int t = seg; t < TT; t += 8) c += (words[t * BB + b] != 0) ? 1 : 0;
        cnt[seg][b] = c;
        __syncthreads();
        if (tid < 64) {
            int s = 0;
            #pragma unroll
            for (int g = 0; g < 8; ++g) s += cnt[g][tid];
            lenArr[tid] = s;
        }
        if (tid == 0) *loss_slot = 0.f;
        return;
    }

    // B-fragment table: Bfrag[ks][lane] = 8 bf16 of W[ks*32 + (lane>>4)*8 + p][lane&15]
    __shared__ uint4 Bfrag[32][64];  // 32 KB
    for (int idx = tid; idx < 32 * 64; idx += 512) {
        const int ks = idx >> 6, l = idx & 63;
        const int col = l & 15, kg2 = l >> 4;
        unsigned u[4];
        #pragma unroll
        for (int p = 0; p < 4; ++p) {
            unsigned lo = 0, hi = 0;
            if (col < KK) {
                const int k0 = ks * 32 + kg2 * 8 + p * 2;
                lo = f2bf(W[(size_t)k0 * KK + col]);
                hi = f2bf(W[(size_t)(k0 + 1) * KK + col]);
            }
            u[p] = lo | (hi << 16);
        }
        Bfrag[ks][l] = make_uint4(u[0], u[1], u[2], u[3]);
    }
    __syncthreads();

    const int wave = tid >> 6, lane = tid & 63;
    const int arow = lane & 15;      // A row within tile (== C col)
    const int kg   = lane >> 4;      // k-group (and C row-group)
    const int row0 = blockIdx.x * 128 + wave * 16;
    const float* ap = wf + (size_t)(row0 + arow) * DD + kg * 8;
    const float bk = bias[arow < KK ? arow : 0];

    f32x4 acc = {0.f, 0.f, 0.f, 0.f};
    float4 fa[4], fb[4];
    #pragma unroll
    for (int p = 0; p < 4; ++p) {
        fa[p] = *reinterpret_cast<const float4*>(ap + p * 32);
        fb[p] = *reinterpret_cast<const float4*>(ap + p * 32 + 4);
    }
    uint4 bcur[8], bnxt[8];
    #pragma unroll
    for (int q = 0; q < 8; ++q) bcur[q] = Bfrag[q][lane];

    #pragma unroll
    for (int ph = 0; ph < 4; ++ph) {
        if (ph < 3) {
            #pragma unroll
            for (int q = 0; q < 8; ++q) bnxt[q] = Bfrag[(ph + 1) * 8 + q][lane];
        }
        #pragma unroll
        for (int q = 0; q < 8; ++q) {
            const int ks = ph * 8 + q;
            const int s = ks & 3;
            bf16x8 afr;
            afr[0] = (short)f2bf(fa[s].x); afr[1] = (short)f2bf(fa[s].y);
            afr[2] = (short)f2bf(fa[s].z); afr[3] = (short)f2bf(fa[s].w);
            afr[4] = (short)f2bf(fb[s].x); afr[5] = (short)f2bf(fb[s].y);
            afr[6] = (short)f2bf(fb[s].z); afr[7] = (short)f2bf(fb[s].w);
            if (ks < 28) {  // keep ~6-8 KB/wave in flight
                fa[s] = *reinterpret_cast<const float4*>(ap + (ks + 4) * 32);
                fb[s] = *reinterpret_cast<const float4*>(ap + (ks + 4) * 32 + 4);
            }
            union { uint4 u; bf16x8 v; } bu;
            bu.u = bcur[q];
            acc = __builtin_amdgcn_mfma_f32_16x16x32_bf16(afr, bu.v, acc, 0, 0, 0);
        }
        #pragma unroll
        for (int q = 0; q < 8; ++q) bcur[q] = bnxt[q];
    }
    // C layout: col = lane&15, row = (lane>>4)*4 + reg  [m89]
    if (arow < KK) {
        #pragma unroll
        for (int r = 0; r < 4; ++r)
            em[(size_t)(row0 + kg * 4 + r) * KK + arow] = acc[r] + bk;
    }
}

// ---------------- Kernel B: per-chunk 10x10 transfer matrices ---------------
// grid 2048: blockIdx = sem*1024 + b*16 + c; 128 threads, (i,j) = tid/10,tid%10.
__global__ __launch_bounds__(128) void k_chunk(
    const float* __restrict__ em, const float* __restrict__ trans,
    const int* __restrict__ lenArr, float* __restrict__ Mlse, float* __restrict__ Mmax) {
    int id = blockIdx.x;
    const bool mx = id >= 1024; id &= 1023;
    const int b = id >> 4, c = id & 15;
    const int len = lenArr[b];
    const int s_lo = c * CL + 1;
    const int s_hi = min(c * CL + CL, len - 1);
    const int ns = s_hi - s_lo + 1;
    if (ns <= 0) return;  // identity chunk: consumers skip it

    __shared__ float Ms[KK][12];
    __shared__ float eml[CL][KK];
    const int tid = threadIdx.x;
    for (int idx = tid; idx < CL * KK; idx += 128) {
        const int sl = idx / KK, j = idx % KK;
        const int s = s_lo + sl;
        eml[sl][j] = (s <= TT - 1) ? em[((size_t)s * BB + b) * KK + j] : 0.f;
    }
    const int i = tid / KK, j = tid % KK;
    const bool act = tid < KK * KK;
    float trc[KK];
    if (act) {
        #pragma unroll
        for (int k = 0; k < KK; ++k) trc[k] = trans[k * KK + j];
    }
    __syncthreads();
    float cur = 0.f;
    if (act) { cur = trans[i * KK + j] + eml[0][j]; Ms[i][j] = cur; }
    __syncthreads();
    for (int sl = 1; sl < ns; ++sl) {
        float row[KK];
        if (act) {
            #pragma unroll
            for (int k = 0; k < KK; ++k) row[k] = Ms[i][k] + trc[k];
        }
        __syncthreads();
        if (act) {
            cur = (mx ? max10(row) : lse10(row)) + eml[sl][j];
            Ms[i][j] = cur;
        }
        __syncthreads();
    }
    if (act) {
        float* out = mx ? Mmax : Mlse;
        out[((size_t)b * NC + c) * 100 + i * KK + j] = cur;
    }
}

// ---------------- Kernel C: merged fold + hist + backtrace + loss -----------
// grid 64 (one block per batch) x 1024 threads (16 waves).
__global__ __launch_bounds__(1024) void k_crf(
    const int* __restrict__ tags, const float* __restrict__ em,
    const float* __restrict__ startv, const float* __restrict__ endv,
    const float* __restrict__ trans, const int* __restrict__ lenArr,
    const float* __restrict__ Mlse, const float* __restrict__ Mmax,
    int* __restrict__ paths, float* __restrict__ loss_slot) {
    const int b = blockIdx.x;
    const int tid = threadIdx.x;
    const int wv = tid >> 6, lane = tid & 63;
    const int len = lenArr[b];

    __shared__ float Ml[NC][100];
    __shared__ float Mm[NC][100];
    __shared__ float eml[NC][CL][KK];
    __shared__ float ub[NC][KK];
    __shared__ uchar hl[NC][CL * KK];
    __shared__ int   Fl[NC][KK];
    __shared__ int   vt[NC + 1];
    __shared__ float em0[KK];
    __shared__ float red[2];

    for (int idx = tid; idx < NC * 100; idx += 1024) {
        Ml[idx / 100][idx % 100] = Mlse[(size_t)b * NC * 100 + idx];
        Mm[idx / 100][idx % 100] = Mmax[(size_t)b * NC * 100 + idx];
    }
    for (int idx = tid; idx < NC * CL * KK; idx += 1024) {
        const int c = idx / (CL * KK), r = idx % (CL * KK);
        const int sl = r / KK, j = r % KK;
        const int s = c * CL + 1 + sl;
        eml[c][sl][j] = (s <= TT - 1) ? em[((size_t)s * BB + b) * KK + j] : 0.f;
    }
    if (tid < KK) em0[tid] = em[(size_t)b * KK + tid];
    __syncthreads();

    if (wv == 0) {  // max-plus fold -> boundary vectors + last tag
        float v[KK];
        #pragma unroll
        for (int i = 0; i < KK; ++i) v[i] = startv[i] + em0[i];
        for (int c = 0; c < NC; ++c) {
            if (lane < KK) ub[c][lane] = v[lane];
            const int s_hi = min(c * CL + CL, len - 1);
            if (s_hi >= c * CL + 1) {
                float nv = 0.f;
                if (lane < KK) {
                    float r[KK];
                    #pragma unroll
                    for (int k = 0; k < KK; ++k) r[k] = v[k] + Mm[c][k * KK + lane];
                    nv = max10(r);
                }
                #pragma unroll
                for (int i = 0; i < KK; ++i) v[i] = __shfl(nv, i);
            }
        }
        float best = v[0] + endv[0];
        int bi = 0;
        #pragma unroll
        for (int i = 1; i < KK; ++i) {
            const float x = v[i] + endv[i];
            if (x > best) { best = x; bi = i; }
        }
        if (lane == 0) vt[NC] = bi;
    } else if (wv == 1) {  // LSE fold -> denominator
        float v[KK];
        #pragma unroll
        for (int i = 0; i < KK; ++i) v[i] = startv[i] + em0[i];
        for (int c = 0; c < NC; ++c) {
            const int s_hi = min(c * CL + CL, len - 1);
            if (s_hi >= c * CL + 1) {
                float nv = 0.f;
                if (lane < KK) {
                    float r[KK];
                    #pragma unroll
                    for (int k = 0; k < KK; ++k) r[k] = v[k] + Ml[c][k * KK + lane];
                    nv = lse10(r);
                }
                #pragma unroll
                for (int i = 0; i < KK; ++i) v[i] = __shfl(nv, i);
            }
        }
        float r[KK];
        #pragma unroll
        for (int i = 0; i < KK; ++i) r[i] = v[i] + endv[i];
        if (lane == 0) red[0] = lse10(r);
    } else if (wv == 2) {  // gold-path numerator
        float part = 0.f;
        for (int t = 1 + lane; t < len; t += 64) {
            const int tp = tags[(t - 1) * BB + b];
            const int tc = tags[t * BB + b];
            part += trans[tp * KK + tc] + eml[(t - 1) >> 5][(t - 1) & 31][tc];
        }
        #pragma unroll
        for (int off = 32; off >= 1; off >>= 1) part += __shfl_xor(part, off);
        if (lane == 0) {
            const int t0 = tags[b];
            const int te = tags[(len - 1) * BB + b];
            red[1] = part + startv[t0] + em0[t0] + endv[te];
        }
    }
    __syncthreads();

    // per-chunk Viterbi re-run from exact boundary vector (wave c owns chunk c)
    {
        const int c = wv;
        const int s_hi = min(c * CL + CL, len - 1);
        const int ns = s_hi - (c * CL + 1) + 1;
        if (ns > 0) {
            float trc[KK];
            if (lane < KK) {
                #pragma unroll
                for (int i = 0; i < KK; ++i) trc[i] = trans[i * KK + lane];
            }
            float s[KK];
            #pragma unroll
            for (int i = 0; i < KK; ++i) s[i] = ub[c][i];
            for (int sl = 0; sl < ns; ++sl) {
                float best = s[0] + trc[0];
                int bi = 0;
                #pragma unroll
                for (int i = 1; i < KK; ++i) {
                    const float x = s[i] + trc[i];
                    if (x > best) { best = x; bi = i; }
                }
                float snew = 0.f;
                if (lane < KK) {
                    snew = best + eml[c][sl][lane];
                    hl[c][sl * KK + lane] = (uchar)bi;
                }
                #pragma unroll
                for (int i = 0; i < KK; ++i) s[i] = __shfl(snew, i);
            }
            if (lane < KK) {  // compose chunk's backtrace map
                int cur = lane;
                for (int sl = ns - 1; sl >= 0; --sl) cur = hl[c][sl * KK + cur];
                Fl[c][lane] = cur;
            }
        }
    }
    __syncthreads();

    if (tid == 0) {  // boundary-tag fold + loss
        int cur = vt[NC];
        for (int c = NC - 1; c >= 0; --c) {
            const int s_hi = min(c * CL + CL, len - 1);
            if (s_hi >= c * CL + 1) cur = Fl[c][cur];
            vt[c] = cur;
        }
        atomicAdd(loss_slot, red[0] - red[1]);
    }
    __syncthreads();

    // emit: wave w writes path slice [32w, 32w+31]
    const int t0 = wv * CL;
    if (lane < CL) {
        const int t = t0 + lane;
        if (t >= len) paths[t * BB + b] = 0;
    }
    if (lane == 0) {
        const int a = min(t0 + CL, len - 1);
        if (a >= t0) {
            int cur = vt[wv + 1];  // = path[a]
            for (int t = a; t >= t0; --t) {
                if (t <= t0 + CL - 1) paths[t * BB + b] = cur;
                if (t > t0) cur = (int)hl[wv][(t - t0 - 1) * KK + cur];
            }
        }
    }
}

extern "C" void kernel_launch(void* const* d_in, const int* in_sizes, int n_in,
                              void* d_out, int out_size, void* d_ws, size_t ws_size,
                              hipStream_t stream) {
    const int*   words  = (const int*)d_in[0];
    const int*   tags   = (const int*)d_in[1];
    const float* wf     = (const float*)d_in[2];
    const float* W      = (const float*)d_in[3];
    const float* bias   = (const float*)d_in[4];
    const float* startv = (const float*)d_in[5];
    const float* endv   = (const float*)d_in[6];
    const float* trans  = (const float*)d_in[7];

    float* em   = (float*)d_ws;                       // 512*64*10 floats
    float* Mlse = em + 327680;                        // 64*16*100
    float* Mmax = Mlse + 102400;                      // 64*16*100
    int*   lenA = (int*)(Mmax + 102400);              // 64

    int*   paths     = (int*)d_out;                   // (T,B) int32 values
    float* loss_slot = ((float*)d_out) + TT * BB;     // scalar f32

    k_emissions<<<257, 512, 0, stream>>>(words, wf, W, bias, em, lenA, loss_slot);
    k_chunk<<<2048, 128, 0, stream>>>(em, trans, lenA, Mlse, Mmax);
    k_crf<<<64, 1024, 0, stream>>>(tags, em, startv, endv, trans, lenA,
                                   Mlse, Mmax, paths, loss_slot);
}